// Round 1
// baseline (310.428 us; speedup 1.0000x reference)
//
#include <hip/hip_runtime.h>

// ---------------------------------------------------------------------------
// BetterGooLayer: mass-spring scan + collapsed FIR path.
//
// Reference collapses to:
//   sim (per b,m,d chain, T=8192):  dir=h-pos; acc=f+k*dir; vel=(vel+acc)*DAMP;
//                                   pos+=vel;  disp=dir; rec += (ms*acc)*mic
//   hf[b,m,t] = rec[b,m,t] + gain * sum_{s=0..255} g[b,m,s]*up_n[b,m,t-s]
//   up_n = |rec| * jax.random.uniform(key(123), ..., -0.01, 0.01)
//   g[b,m,s] = sum_f (sum_d bias[m,d]*tfm[m,d,f]) * filters[b,f,s]
//
// Sim is parallelized over t via a 3-phase chunked linear scan (LTI 2x2 system).
// ---------------------------------------------------------------------------

#define NS    8192
#define BB    4
#define MM    64
#define DD    8
#define NF    8
#define FL    256
#define CHUNKS 64
#define CLEN   128          // CHUNKS*CLEN == NS
#define NCHAIN (BB*MM*DD)   // 2048
#define DAMP  0.9998f

#define REC_OFF  0
#define DISP_OFF (BB*MM*NS)                 // 2097152
#define HF_OFF   (DISP_OFF + BB*MM*DD*NS)   // 18874368

// ---------------- threefry2x32 (JAX, partitionable counters) ----------------
__device__ __forceinline__ unsigned rotl32(unsigned x, int r) {
    return (x << r) | (x >> (32 - r));
}

// jax.random.uniform(jax.random.key(123), (B,M,NS), minval=-0.01, maxval=0.01)
// partitionable mode: counter = (hi=0, lo=idx), bits = y0 ^ y1.
__device__ float jax_noise(unsigned idx) {
    const unsigned ks0 = 0u;
    const unsigned ks1 = 123u;
    const unsigned ks2 = 0x1BD11BDAu ^ 0u ^ 123u;
    unsigned x0 = 0u  + ks0;
    unsigned x1 = idx + ks1;
#define TF_RND(r) { x0 += x1; x1 = rotl32(x1, r); x1 ^= x0; }
    TF_RND(13) TF_RND(15) TF_RND(26) TF_RND(6)
    x0 += ks1; x1 += ks2 + 1u;
    TF_RND(17) TF_RND(29) TF_RND(16) TF_RND(24)
    x0 += ks2; x1 += ks0 + 2u;
    TF_RND(13) TF_RND(15) TF_RND(26) TF_RND(6)
    x0 += ks0; x1 += ks1 + 3u;
    TF_RND(17) TF_RND(29) TF_RND(16) TF_RND(24)
    x0 += ks1; x1 += ks2 + 4u;
    TF_RND(13) TF_RND(15) TF_RND(26) TF_RND(6)
    x0 += ks2; x1 += ks0 + 5u;
#undef TF_RND
    unsigned bits = x0 ^ x1;
    float u = __uint_as_float((bits >> 9) | 0x3f800000u) - 1.0f;  // [0,1)
    return fmaxf(-0.01f, u * 0.02f - 0.01f);
}

// ---------------- Phase A: per-(chain,chunk) forced response from zero state
__global__ __launch_bounds__(256) void sim_phaseA(
    const float* __restrict__ forces, const float* __restrict__ hm,
    const float* __restrict__ home,   const float* __restrict__ cs,
    const float* __restrict__ masses, const float* __restrict__ tens,
    float2* __restrict__ qout)
{
    int tid = blockIdx.x * 256 + threadIdx.x;   // 131072 threads
    int ch  = tid >> 6;        // chain = (b*M+m)*D+d
    int c   = tid & 63;        // chunk
    int m = (ch >> 3) & (MM - 1);
    int d = ch & (DD - 1);
    float k   = tens[m * DD + d] / masses[m];
    float csm = cs[m];
    float hd  = home[d];
    size_t base = (size_t)ch * NS + (size_t)c * CLEN;
    const float4* f4 = (const float4*)(forces + base);
    const float4* h4 = (const float4*)(hm + base);
    float pos = 0.f, vel = 0.f;
    float4 fv = f4[0], hv = h4[0];
    for (int g = 0; g < CLEN / 4; ++g) {
        float4 fn = fv, hn = hv;
        if (g + 1 < CLEN / 4) { fn = f4[g + 1]; hn = h4[g + 1]; }
        float fts[4] = {fv.x, fv.y, fv.z, fv.w};
        float hts[4] = {hv.x, hv.y, hv.z, hv.w};
#pragma unroll
        for (int j = 0; j < 4; ++j) {
            float ht  = fmaf(hts[j], csm, hd);
            float dir = ht - pos;
            float acc = fmaf(k, dir, fts[j]);
            vel = (vel + acc) * DAMP;
            pos += vel;
        }
        fv = fn; hv = hn;
    }
    qout[tid] = make_float2(pos, vel);
}

// ---------------- Phase B: per-chain scan over chunks (state at chunk starts)
__global__ __launch_bounds__(256) void sim_phaseB(
    const float* __restrict__ masses, const float* __restrict__ tens,
    const float2* __restrict__ q, float2* __restrict__ s0)
{
    int ch = blockIdx.x * 256 + threadIdx.x;
    if (ch >= NCHAIN) return;
    int m = (ch >> 3) & (MM - 1);
    int d = ch & (DD - 1);
    float kf = tens[m * DD + d] / masses[m];
    double k  = (double)kf;
    double dm = (double)DAMP;
    // one step: pos' = (1-dm*k)pos + dm*vel + w ; vel' = -dm*k*pos + dm*vel + w
    double p11 = 1.0 - dm * k, p12 = dm, p21 = -dm * k, p22 = dm;
    // P = A^128 via 7 squarings
    for (int i = 0; i < 7; ++i) {
        double n11 = p11 * p11 + p12 * p21;
        double n12 = p11 * p12 + p12 * p22;
        double n21 = p21 * p11 + p22 * p21;
        double n22 = p21 * p12 + p22 * p22;
        p11 = n11; p12 = n12; p21 = n21; p22 = n22;
    }
    double sx = 0.0, sy = 0.0;
    for (int c = 0; c < CHUNKS; ++c) {
        s0[ch * CHUNKS + c] = make_float2((float)sx, (float)sy);
        float2 qc = q[ch * CHUNKS + c];
        double nx = p11 * sx + p12 * sy + (double)qc.x;
        double ny = p21 * sx + p22 * sy + (double)qc.y;
        sx = nx; sy = ny;
    }
}

// ---------------- Phase C: re-simulate chunks from true state, write outputs
// Block: 256 thr = 8 d x 32 chunks; grid 512 = 256 (b,m) x 2 chunk-halves.
__global__ __launch_bounds__(256) void sim_phaseC(
    const float* __restrict__ forces, const float* __restrict__ hm,
    const float* __restrict__ home,   const float* __restrict__ cs,
    const float* __restrict__ masses, const float* __restrict__ tens,
    const float* __restrict__ mics,   const float2* __restrict__ s0,
    float* __restrict__ out)
{
    int bm   = blockIdx.x >> 1;
    int half = blockIdx.x & 1;
    int tx = threadIdx.x;
    int d  = tx & 7;
    int cc = tx >> 3;              // 0..31
    int c  = half * 32 + cc;
    int m  = bm & (MM - 1);
    int ch = bm * DD + d;
    float ms  = masses[m];
    float k   = tens[m * DD + d] / ms;
    float mic = mics[m * DD + d];
    float csm = cs[m];
    float hd  = home[d];
    float2 s = s0[ch * CHUNKS + c];
    float pos = s.x, vel = s.y;
    size_t base = (size_t)ch * NS + (size_t)c * CLEN;
    const float4* f4 = (const float4*)(forces + base);
    const float4* h4 = (const float4*)(hm + base);
    float4* disp4 = (float4*)(out + DISP_OFF + base);
    float4* rec4  = (float4*)(out + REC_OFF + (size_t)bm * NS + (size_t)c * CLEN);
    float4 fv = f4[0], hv = h4[0];
    for (int g = 0; g < CLEN / 4; ++g) {
        float4 fn = fv, hn = hv;
        if (g + 1 < CLEN / 4) { fn = f4[g + 1]; hn = h4[g + 1]; }
        float fts[4] = {fv.x, fv.y, fv.z, fv.w};
        float hts[4] = {hv.x, hv.y, hv.z, hv.w};
        float dout[4], rout[4];
#pragma unroll
        for (int j = 0; j < 4; ++j) {
            float ht  = fmaf(hts[j], csm, hd);
            float dir = ht - pos;
            float acc = fmaf(k, dir, fts[j]);
            vel = (vel + acc) * DAMP;
            pos += vel;
            dout[j] = dir;
            float contrib = (ms * acc) * mic;          // f_seq * mic
            contrib += __shfl_xor(contrib, 1, 64);     // reduce over d (lanes 0..7)
            contrib += __shfl_xor(contrib, 2, 64);
            contrib += __shfl_xor(contrib, 4, 64);
            rout[j] = contrib;
        }
        disp4[g] = make_float4(dout[0], dout[1], dout[2], dout[3]);
        if (d == 0) rec4[g] = make_float4(rout[0], rout[1], rout[2], rout[3]);
        fv = fn; hv = hn;
    }
}

// ---------------- HF kernel: noise + combined 256-tap FIR + lf add
// Block per (b,m) row; LDS-staged up_n with 256-zero left pad.
__global__ __launch_bounds__(256) void hf_kernel(
    const float* __restrict__ rec,     // out + REC_OFF
    const float* __restrict__ filters, const float* __restrict__ tfm,
    const float* __restrict__ bias,    const float* __restrict__ hf_gain,
    float* __restrict__ hf)            // out + HF_OFF
{
    __shared__ float up[FL + NS];      // [0,256) zero pad, then up_n row
    __shared__ float gtap[FL];
    int bm = blockIdx.x;
    int b  = bm >> 6;
    int m  = bm & 63;
    int tx = threadIdx.x;
    up[tx] = 0.f;                      // left pad
    // combined filter tap g[tx] = sum_f (sum_d bias*tfm) * filters[b,f,tx]
    float gs = 0.f;
#pragma unroll
    for (int f = 0; f < NF; ++f) {
        float mix = 0.f;
#pragma unroll
        for (int dd = 0; dd < DD; ++dd)
            mix = fmaf(bias[m * DD + dd], tfm[(m * DD + dd) * NF + f], mix);
        gs = fmaf(mix, filters[(b * NF + f) * FL + tx], gs);
    }
    gtap[tx] = gs;
    // up_n = |rec| * noise
    const float* rrow = rec + (size_t)bm * NS;
    for (int t = tx; t < NS; t += 256) {
        float nz = jax_noise((unsigned)(bm * NS + t));
        up[FL + t] = fabsf(rrow[t]) * nz;
    }
    __syncthreads();
    float gain = hf_gain[0];
    float* hrow = hf + (size_t)bm * NS;
    for (int gi = 0; gi < 4; ++gi) {
        int t0 = (gi * 256 + tx) * 8;          // 8 consecutive outputs/thread
        float acc[8] = {0, 0, 0, 0, 0, 0, 0, 0};
        float w[8];
#pragma unroll
        for (int j = 0; j < 8; ++j) w[j] = up[FL + t0 - 255 + j];
#pragma unroll 8
        for (int s = 255; s >= 1; --s) {
            float gv = gtap[s];
#pragma unroll
            for (int j = 0; j < 8; ++j) acc[j] = fmaf(gv, w[j], acc[j]);
#pragma unroll
            for (int j = 0; j < 7; ++j) w[j] = w[j + 1];
            w[7] = up[FL + t0 + 8 - s];
        }
        float g0 = gtap[0];
#pragma unroll
        for (int j = 0; j < 8; ++j) acc[j] = fmaf(g0, w[j], acc[j]);
        float4 r0 = *(const float4*)(rrow + t0);
        float4 r1 = *(const float4*)(rrow + t0 + 4);
        float4 o0 = make_float4(fmaf(gain, acc[0], r0.x), fmaf(gain, acc[1], r0.y),
                                fmaf(gain, acc[2], r0.z), fmaf(gain, acc[3], r0.w));
        float4 o1 = make_float4(fmaf(gain, acc[4], r1.x), fmaf(gain, acc[5], r1.y),
                                fmaf(gain, acc[6], r1.z), fmaf(gain, acc[7], r1.w));
        *(float4*)(hrow + t0)     = o0;
        *(float4*)(hrow + t0 + 4) = o1;
    }
}

extern "C" void kernel_launch(void* const* d_in, const int* in_sizes, int n_in,
                              void* d_out, int out_size, void* d_ws, size_t ws_size,
                              hipStream_t stream)
{
    const float* forces  = (const float*)d_in[0];
    const float* hm      = (const float*)d_in[1];
    const float* filters = (const float*)d_in[2];
    const float* home    = (const float*)d_in[3];
    const float* cs      = (const float*)d_in[4];
    const float* masses  = (const float*)d_in[5];
    const float* tens    = (const float*)d_in[6];
    const float* mics    = (const float*)d_in[7];
    const float* tfm     = (const float*)d_in[8];
    const float* bias    = (const float*)d_in[9];
    const float* gain    = (const float*)d_in[10];
    float* out = (float*)d_out;

    float2* q  = (float2*)d_ws;                 // NCHAIN*CHUNKS float2 = 1 MiB
    float2* s0 = q + NCHAIN * CHUNKS;           // another 1 MiB

    sim_phaseA<<<(NCHAIN * CHUNKS) / 256, 256, 0, stream>>>(
        forces, hm, home, cs, masses, tens, q);
    sim_phaseB<<<NCHAIN / 256, 256, 0, stream>>>(masses, tens, q, s0);
    sim_phaseC<<<BB * MM * 2, 256, 0, stream>>>(
        forces, hm, home, cs, masses, tens, mics, s0, out);
    hf_kernel<<<BB * MM, 256, 0, stream>>>(
        out + REC_OFF, filters, tfm, bias, gain, out + HF_OFF);
}

// Round 3
// 200.808 us; speedup vs baseline: 1.5459x; 1.5459x over previous
//
#include <hip/hip_runtime.h>

// ---------------------------------------------------------------------------
// BetterGooLayer: mass-spring chunked linear scan + collapsed FIR path.
// R2: LDS-staged coalesced global I/O for both sim passes (R1 showed 4x read /
// 3x write HBM amplification from 512B-strided 16B accesses).
// R3: identical resubmit — R2 bench died to container failure before running.
// ---------------------------------------------------------------------------

#define NS    8192
#define BB    4
#define MM    64
#define DD    8
#define NF    8
#define FL    256
#define CHUNKS 64
#define CLEN   128          // CHUNKS*CLEN == NS
#define NCHAIN (BB*MM*DD)   // 2048
#define DAMP  0.9998f
#define W     16            // timesteps per LDS tile
#define PW    20            // padded tile stride (floats)
#define TILES (CLEN/W)      // 8

#define REC_OFF  0
#define DISP_OFF (BB*MM*NS)                 // 2097152
#define HF_OFF   (DISP_OFF + BB*MM*DD*NS)   // 18874368

// ---------------- threefry2x32 (JAX, partitionable counters) ----------------
__device__ __forceinline__ unsigned rotl32(unsigned x, int r) {
    return (x << r) | (x >> (32 - r));
}

__device__ float jax_noise(unsigned idx) {
    const unsigned ks0 = 0u;
    const unsigned ks1 = 123u;
    const unsigned ks2 = 0x1BD11BDAu ^ 0u ^ 123u;
    unsigned x0 = 0u  + ks0;
    unsigned x1 = idx + ks1;
#define TF_RND(r) { x0 += x1; x1 = rotl32(x1, r); x1 ^= x0; }
    TF_RND(13) TF_RND(15) TF_RND(26) TF_RND(6)
    x0 += ks1; x1 += ks2 + 1u;
    TF_RND(17) TF_RND(29) TF_RND(16) TF_RND(24)
    x0 += ks2; x1 += ks0 + 2u;
    TF_RND(13) TF_RND(15) TF_RND(26) TF_RND(6)
    x0 += ks0; x1 += ks1 + 3u;
    TF_RND(17) TF_RND(29) TF_RND(16) TF_RND(24)
    x0 += ks1; x1 += ks2 + 4u;
    TF_RND(13) TF_RND(15) TF_RND(26) TF_RND(6)
    x0 += ks2; x1 += ks0 + 5u;
#undef TF_RND
    unsigned bits = x0 ^ x1;
    float u = __uint_as_float((bits >> 9) | 0x3f800000u) - 1.0f;  // [0,1)
    return fmaxf(-0.01f, u * 0.02f - 0.01f);
}

// ---------------- sim kernel (templated: q-pass or output-pass) -------------
// Block: 256 thr = 32 chunks x 8 d; grid 512 = 256 (b,m) x 2 chunk-halves.
// Inputs/outputs staged through LDS in W=16-step tiles so global accesses are
// 64B-contiguous per 4 lanes (L2 merges the 128B-line halves across tiles).
template <bool OUT>
__global__ __launch_bounds__(256) void sim_kernel(
    const float* __restrict__ forces, const float* __restrict__ hm,
    const float* __restrict__ home,   const float* __restrict__ cs,
    const float* __restrict__ masses, const float* __restrict__ tens,
    const float* __restrict__ mics,   const float2* __restrict__ s0,
    float2* __restrict__ qout,        float* __restrict__ out)
{
    __shared__ __align__(16) float lF[32 * 8 * PW];
    __shared__ __align__(16) float lH[32 * 8 * PW];
    __shared__ __align__(16) float lD[32 * 8 * PW];
    __shared__ float lR[32 * 17];

    int bm   = blockIdx.x >> 1;
    int half = blockIdx.x & 1;
    int tid  = threadIdx.x;
    int cl = tid >> 3;          // chunk-local 0..31
    int d  = tid & 7;
    int m  = bm & (MM - 1);

    float ms  = masses[m];
    float k   = tens[m * DD + d] / ms;
    float csm = cs[m];
    float hd  = home[d];
    float mic = 0.f;

    int ch = bm * DD + d;
    int c  = half * 32 + cl;
    float pos = 0.f, vel = 0.f;
    if (OUT) {
        float2 s = s0[ch * CHUNKS + c];
        pos = s.x; vel = s.y;
        mic = mics[m * DD + d];
    }

    // staging-lane mapping: each thread loads 4 float4 per array per tile
    int ld_d   = (tid >> 2) & 7;
    int ld_e   = tid & 3;
    int ld_cl8 = tid >> 5;      // 0..7
    size_t goff = (size_t)(bm * DD + ld_d) * NS
                + (size_t)(half * 32 + ld_cl8) * CLEN + ld_e * 4;
    const float* fbase = forces + goff;
    const float* hbase = hm + goff;

    float4 rf[4], rh[4];
#pragma unroll
    for (int p = 0; p < 4; ++p) {
        rf[p] = *(const float4*)(fbase + p * 8 * CLEN);
        rh[p] = *(const float4*)(hbase + p * 8 * CLEN);
    }

    for (int t = 0; t < TILES; ++t) {
        // write staged registers to LDS
#pragma unroll
        for (int p = 0; p < 4; ++p) {
            int li = ((p * 8 + ld_cl8) * 8 + ld_d) * PW + ld_e * 4;
            *(float4*)(lF + li) = rf[p];
            *(float4*)(lH + li) = rh[p];
        }
        __syncthreads();
        // issue next tile's loads early (latency hides under sim + flush)
        if (t + 1 < TILES) {
#pragma unroll
            for (int p = 0; p < 4; ++p) {
                rf[p] = *(const float4*)(fbase + (t + 1) * W + p * 8 * CLEN);
                rh[p] = *(const float4*)(hbase + (t + 1) * W + p * 8 * CLEN);
            }
        }
        // simulate W steps from LDS
        int lbase = (cl * 8 + d) * PW;
#pragma unroll
        for (int g = 0; g < 4; ++g) {
            float4 fv = *(const float4*)(lF + lbase + g * 4);
            float4 hv = *(const float4*)(lH + lbase + g * 4);
            float ff[4] = {fv.x, fv.y, fv.z, fv.w};
            float hh[4] = {hv.x, hv.y, hv.z, hv.w};
            float dd_[4];
#pragma unroll
            for (int u = 0; u < 4; ++u) {
                float ht  = fmaf(hh[u], csm, hd);
                float dir = ht - pos;
                float acc = fmaf(k, dir, ff[u]);
                vel = (vel + acc) * DAMP;
                pos += vel;
                if (OUT) {
                    dd_[u] = dir;
                    float contrib = (ms * acc) * mic;
                    contrib += __shfl_xor(contrib, 1, 64);
                    contrib += __shfl_xor(contrib, 2, 64);
                    contrib += __shfl_xor(contrib, 4, 64);
                    if (d == 0) lR[cl * 17 + g * 4 + u] = contrib;
                }
            }
            if (OUT)
                *(float4*)(lD + lbase + g * 4) =
                    make_float4(dd_[0], dd_[1], dd_[2], dd_[3]);
        }
        __syncthreads();
        if (OUT) {
            // flush disp tile (same lane mapping as staging loads)
#pragma unroll
            for (int p = 0; p < 4; ++p) {
                int li = ((p * 8 + ld_cl8) * 8 + ld_d) * PW + ld_e * 4;
                float4 v = *(const float4*)(lD + li);
                *(float4*)(out + DISP_OFF + goff + (size_t)p * 8 * CLEN
                           + (size_t)t * W) = v;
            }
            // flush rec tile: 32 chunks x 16 steps
            float* recrow = out + REC_OFF + (size_t)bm * NS
                          + (size_t)half * 32 * CLEN + (size_t)t * W;
#pragma unroll
            for (int p = 0; p < 2; ++p) {
                int i   = p * 256 + tid;
                int rcl = i >> 4;
                int j   = i & 15;
                recrow[rcl * CLEN + j] = lR[rcl * 17 + j];
            }
        }
    }
    if (!OUT) qout[ch * CHUNKS + c] = make_float2(pos, vel);
}

// ---------------- Phase B: per-chain scan over chunks (f64) -----------------
__global__ __launch_bounds__(256) void sim_phaseB(
    const float* __restrict__ masses, const float* __restrict__ tens,
    const float2* __restrict__ q, float2* __restrict__ s0)
{
    int ch = blockIdx.x * 256 + threadIdx.x;
    if (ch >= NCHAIN) return;
    int m = (ch >> 3) & (MM - 1);
    int d = ch & (DD - 1);
    float kf = tens[m * DD + d] / masses[m];
    double k  = (double)kf;
    double dm = (double)DAMP;
    double p11 = 1.0 - dm * k, p12 = dm, p21 = -dm * k, p22 = dm;
    for (int i = 0; i < 7; ++i) {   // P = A^128
        double n11 = p11 * p11 + p12 * p21;
        double n12 = p11 * p12 + p12 * p22;
        double n21 = p21 * p11 + p22 * p21;
        double n22 = p21 * p12 + p22 * p22;
        p11 = n11; p12 = n12; p21 = n21; p22 = n22;
    }
    double sx = 0.0, sy = 0.0;
    for (int c = 0; c < CHUNKS; ++c) {
        s0[ch * CHUNKS + c] = make_float2((float)sx, (float)sy);
        float2 qc = q[ch * CHUNKS + c];
        double nx = p11 * sx + p12 * sy + (double)qc.x;
        double ny = p21 * sx + p22 * sy + (double)qc.y;
        sx = nx; sy = ny;
    }
}

// ---------------- HF kernel: noise + combined 256-tap FIR + lf add ----------
__global__ __launch_bounds__(256) void hf_kernel(
    const float* __restrict__ rec,
    const float* __restrict__ filters, const float* __restrict__ tfm,
    const float* __restrict__ bias,    const float* __restrict__ hf_gain,
    float* __restrict__ hf)
{
    __shared__ float up[FL + NS];
    __shared__ float gtap[FL];
    int bm = blockIdx.x;
    int b  = bm >> 6;
    int m  = bm & 63;
    int tx = threadIdx.x;
    up[tx] = 0.f;
    float gs = 0.f;
#pragma unroll
    for (int f = 0; f < NF; ++f) {
        float mix = 0.f;
#pragma unroll
        for (int dd = 0; dd < DD; ++dd)
            mix = fmaf(bias[m * DD + dd], tfm[(m * DD + dd) * NF + f], mix);
        gs = fmaf(mix, filters[(b * NF + f) * FL + tx], gs);
    }
    gtap[tx] = gs;
    const float* rrow = rec + (size_t)bm * NS;
    for (int t = tx; t < NS; t += 256) {
        float nz = jax_noise((unsigned)(bm * NS + t));
        up[FL + t] = fabsf(rrow[t]) * nz;
    }
    __syncthreads();
    float gain = hf_gain[0];
    float* hrow = hf + (size_t)bm * NS;
    for (int gi = 0; gi < 4; ++gi) {
        int t0 = (gi * 256 + tx) * 8;
        float acc[8] = {0, 0, 0, 0, 0, 0, 0, 0};
        float w[8];
#pragma unroll
        for (int j = 0; j < 8; ++j) w[j] = up[FL + t0 - 255 + j];
#pragma unroll 8
        for (int s = 255; s >= 1; --s) {
            float gv = gtap[s];
#pragma unroll
            for (int j = 0; j < 8; ++j) acc[j] = fmaf(gv, w[j], acc[j]);
#pragma unroll
            for (int j = 0; j < 7; ++j) w[j] = w[j + 1];
            w[7] = up[FL + t0 + 8 - s];
        }
        float g0 = gtap[0];
#pragma unroll
        for (int j = 0; j < 8; ++j) acc[j] = fmaf(g0, w[j], acc[j]);
        float4 r0 = *(const float4*)(rrow + t0);
        float4 r1 = *(const float4*)(rrow + t0 + 4);
        float4 o0 = make_float4(fmaf(gain, acc[0], r0.x), fmaf(gain, acc[1], r0.y),
                                fmaf(gain, acc[2], r0.z), fmaf(gain, acc[3], r0.w));
        float4 o1 = make_float4(fmaf(gain, acc[4], r1.x), fmaf(gain, acc[5], r1.y),
                                fmaf(gain, acc[6], r1.z), fmaf(gain, acc[7], r1.w));
        *(float4*)(hrow + t0)     = o0;
        *(float4*)(hrow + t0 + 4) = o1;
    }
}

extern "C" void kernel_launch(void* const* d_in, const int* in_sizes, int n_in,
                              void* d_out, int out_size, void* d_ws, size_t ws_size,
                              hipStream_t stream)
{
    const float* forces  = (const float*)d_in[0];
    const float* hm      = (const float*)d_in[1];
    const float* filters = (const float*)d_in[2];
    const float* home    = (const float*)d_in[3];
    const float* cs      = (const float*)d_in[4];
    const float* masses  = (const float*)d_in[5];
    const float* tens    = (const float*)d_in[6];
    const float* mics    = (const float*)d_in[7];
    const float* tfm     = (const float*)d_in[8];
    const float* bias    = (const float*)d_in[9];
    const float* gain    = (const float*)d_in[10];
    float* out = (float*)d_out;

    float2* q  = (float2*)d_ws;
    float2* s0 = q + NCHAIN * CHUNKS;

    sim_kernel<false><<<BB * MM * 2, 256, 0, stream>>>(
        forces, hm, home, cs, masses, tens, nullptr, nullptr, q, nullptr);
    sim_phaseB<<<NCHAIN / 256, 256, 0, stream>>>(masses, tens, q, s0);
    sim_kernel<true><<<BB * MM * 2, 256, 0, stream>>>(
        forces, hm, home, cs, masses, tens, mics, s0, nullptr, out);
    hf_kernel<<<BB * MM, 256, 0, stream>>>(
        out + REC_OFF, filters, tfm, bias, gain, out + HF_OFF);
}

// Round 4
// 115.768 us; speedup vs baseline: 2.6815x; 1.7346x over previous
//
#include <hip/hip_runtime.h>

// ---------------------------------------------------------------------------
// BetterGooLayer R4: wave-parallel affine scan for the mass-spring recurrence.
//   s' = A s + w*(1,1),  A = [[1-dk, d],[-dk, d]] lane-uniform per chain.
// 2 timesteps/lane, 128-step chunk per wave (64 chunks — same f64 rebase
// cadence as the passing R3 kernel). Coalesced float2 loads, no LDS staging,
// no barriers in phase A. Phase C: shfl_up inclusive scan + 2-sample re-walk.
// hf FIR split 4 segments/row for 4 blocks/CU.
// ---------------------------------------------------------------------------

#define NS    8192
#define BB    4
#define MM    64
#define DD    8
#define NF    8
#define FL    256
#define CHUNKS 64
#define CLEN   128          // 2 samples/lane * 64 lanes
#define NCHAIN (BB*MM*DD)   // 2048
#define DAMP  0.9998f
#define SEG   2048          // hf segment length

#define REC_OFF  0
#define DISP_OFF (BB*MM*NS)                 // 2097152
#define HF_OFF   (DISP_OFF + BB*MM*DD*NS)   // 18874368

struct Mat { float a, b, c, d; };   // [[a,b],[c,d]]
__device__ __forceinline__ Mat matmul(Mat x, Mat y) {
    Mat r;
    r.a = fmaf(x.a, y.a, x.b * y.c);
    r.b = fmaf(x.a, y.b, x.b * y.d);
    r.c = fmaf(x.c, y.a, x.d * y.c);
    r.d = fmaf(x.c, y.b, x.d * y.d);
    return r;
}
// (A^2)^e via bit-product over precomputed squarings M[r] = (A^2)^(2^r)
__device__ __forceinline__ Mat mat_pow_bits(const Mat* M, int e) {
    Mat p = {1.f, 0.f, 0.f, 1.f};
#pragma unroll
    for (int r = 0; r < 6; ++r)
        if ((e >> r) & 1) p = matmul(p, M[r]);
    return p;
}

// ---------------- threefry2x32 (JAX, partitionable counters) ----------------
__device__ __forceinline__ unsigned rotl32(unsigned x, int r) {
    return (x << r) | (x >> (32 - r));
}
__device__ float jax_noise(unsigned idx) {
    const unsigned ks0 = 0u;
    const unsigned ks1 = 123u;
    const unsigned ks2 = 0x1BD11BDAu ^ 0u ^ 123u;
    unsigned x0 = 0u  + ks0;
    unsigned x1 = idx + ks1;
#define TF_RND(r) { x0 += x1; x1 = rotl32(x1, r); x1 ^= x0; }
    TF_RND(13) TF_RND(15) TF_RND(26) TF_RND(6)
    x0 += ks1; x1 += ks2 + 1u;
    TF_RND(17) TF_RND(29) TF_RND(16) TF_RND(24)
    x0 += ks2; x1 += ks0 + 2u;
    TF_RND(13) TF_RND(15) TF_RND(26) TF_RND(6)
    x0 += ks0; x1 += ks1 + 3u;
    TF_RND(17) TF_RND(29) TF_RND(16) TF_RND(24)
    x0 += ks1; x1 += ks2 + 4u;
    TF_RND(13) TF_RND(15) TF_RND(26) TF_RND(6)
    x0 += ks2; x1 += ks0 + 5u;
#undef TF_RND
    unsigned bits = x0 ^ x1;
    float u = __uint_as_float((bits >> 9) | 0x3f800000u) - 1.0f;  // [0,1)
    return fmaxf(-0.01f, u * 0.02f - 0.01f);
}

// ---------------- Phase A: per-chunk forced response (weighted reduction) ---
// q_c = sum_j (A^2)^(63-j) * W_j,  W_j = A*w_{2j}*u + w_{2j+1}*u,  u=(1,1).
// Wave handles one chain, 16 chunks. 8192 waves = 2048 blocks x 4 waves.
__global__ __launch_bounds__(256) void sim_phaseA(
    const float* __restrict__ forces, const float* __restrict__ hm,
    const float* __restrict__ home,   const float* __restrict__ cs,
    const float* __restrict__ masses, const float* __restrict__ tens,
    float2* __restrict__ qout)
{
    int wave_id = blockIdx.x * 4 + (threadIdx.x >> 6);
    int lane = threadIdx.x & 63;
    int ch   = wave_id >> 2;        // chain
    int slot = wave_id & 3;
    int m = (ch >> 3) & (MM - 1);
    int d = ch & (DD - 1);
    float k   = tens[m * DD + d] / masses[m];
    float csm = cs[m];
    float hd  = home[d];

    Mat A = {1.f - DAMP * k, DAMP, -DAMP * k, DAMP};
    Mat M[6];
    M[0] = matmul(A, A);
#pragma unroll
    for (int r = 1; r < 6; ++r) M[r] = matmul(M[r - 1], M[r - 1]);
    Mat P = mat_pow_bits(M, 63 - lane);     // (A^2)^(63-lane)
    float aux = A.a + A.b;                  // A*(1,1)
    float auy = A.c + A.d;

    size_t base = (size_t)ch * NS;
    const float2* f2p = (const float2*)(forces + base);
    const float2* h2p = (const float2*)(hm + base);
    int c0 = slot * 16;

    float2 fv = f2p[c0 * 64 + lane], hv = h2p[c0 * 64 + lane];
    for (int c = c0; c < c0 + 16; ++c) {
        float2 fc = fv, hc = hv;
        if (c + 1 < c0 + 16) {
            fv = f2p[(c + 1) * 64 + lane];
            hv = h2p[(c + 1) * 64 + lane];
        }
        float h0 = fmaf(hc.x, csm, hd), h1 = fmaf(hc.y, csm, hd);
        float w0 = DAMP * fmaf(k, h0, fc.x);
        float w1 = DAMP * fmaf(k, h1, fc.y);
        float Wx = fmaf(w0, aux, w1);
        float Wy = fmaf(w0, auy, w1);
        float cx = fmaf(P.a, Wx, P.b * Wy);
        float cy = fmaf(P.c, Wx, P.d * Wy);
#pragma unroll
        for (int o = 1; o < 64; o <<= 1) {
            cx += __shfl_xor(cx, o, 64);
            cy += __shfl_xor(cy, o, 64);
        }
        if (lane == 0) qout[ch * CHUNKS + c] = make_float2(cx, cy);
    }
}

// ---------------- Phase B: per-chain f64 scan over chunks -------------------
__global__ __launch_bounds__(256) void sim_phaseB(
    const float* __restrict__ masses, const float* __restrict__ tens,
    const float2* __restrict__ q, float2* __restrict__ s0)
{
    int ch = blockIdx.x * 256 + threadIdx.x;
    if (ch >= NCHAIN) return;
    int m = (ch >> 3) & (MM - 1);
    int d = ch & (DD - 1);
    float kf = tens[m * DD + d] / masses[m];
    double k  = (double)kf;
    double dm = (double)DAMP;
    double p11 = 1.0 - dm * k, p12 = dm, p21 = -dm * k, p22 = dm;
    for (int i = 0; i < 7; ++i) {   // P = A^128
        double n11 = p11 * p11 + p12 * p21;
        double n12 = p11 * p12 + p12 * p22;
        double n21 = p21 * p11 + p22 * p21;
        double n22 = p21 * p12 + p22 * p22;
        p11 = n11; p12 = n12; p21 = n21; p22 = n22;
    }
    double sx = 0.0, sy = 0.0;
    for (int c = 0; c < CHUNKS; ++c) {
        s0[ch * CHUNKS + c] = make_float2((float)sx, (float)sy);
        float2 qc = q[ch * CHUNKS + c];
        double nx = p11 * sx + p12 * sy + (double)qc.x;
        double ny = p21 * sx + p22 * sy + (double)qc.y;
        sx = nx; sy = ny;
    }
}

// ---------------- Phase C: scan + re-walk, write disp/rec -------------------
// Block 512 = 8 waves (one per d of one bm); grid 256 bm x 8 chunk-groups.
__global__ __launch_bounds__(512) void sim_phaseC(
    const float* __restrict__ forces, const float* __restrict__ hm,
    const float* __restrict__ home,   const float* __restrict__ cs,
    const float* __restrict__ masses, const float* __restrict__ tens,
    const float* __restrict__ mics,   const float2* __restrict__ s0,
    float* __restrict__ out)
{
    __shared__ float lR[DD][CLEN + 4];
    int bm  = blockIdx.x >> 3;
    int grp = blockIdx.x & 7;
    int tid = threadIdx.x;
    int d    = tid >> 6;
    int lane = tid & 63;
    int m  = bm & (MM - 1);
    int ch = bm * DD + d;
    float ms  = masses[m];
    float k   = tens[m * DD + d] / ms;
    float csm = cs[m];
    float hd  = home[d];
    float mm  = ms * mics[m * DD + d];

    Mat A = {1.f - DAMP * k, DAMP, -DAMP * k, DAMP};
    Mat M[6];
    M[0] = matmul(A, A);
#pragma unroll
    for (int r = 1; r < 6; ++r) M[r] = matmul(M[r - 1], M[r - 1]);
    Mat P = mat_pow_bits(M, lane);          // (A^2)^lane

    size_t base = (size_t)ch * NS;
    const float2* f2p = (const float2*)(forces + base);
    const float2* h2p = (const float2*)(hm + base);
    float2* disp2 = (float2*)(out + DISP_OFF + base);
    int c0 = grp * 8;

    float2 fv = f2p[c0 * 64 + lane], hv = h2p[c0 * 64 + lane];
    for (int ci = 0; ci < 8; ++ci) {
        int c = c0 + ci;
        float2 fc = fv, hc = hv;
        if (ci < 7) {
            fv = f2p[(c + 1) * 64 + lane];
            hv = h2p[(c + 1) * 64 + lane];
        }
        float2 s0v = s0[ch * CHUNKS + c];
        float h0 = fmaf(hc.x, csm, hd), h1 = fmaf(hc.y, csm, hd);
        float w0 = DAMP * fmaf(k, h0, fc.x);
        float w1 = DAMP * fmaf(k, h1, fc.y);
        float Sx = fmaf(w0, A.a + A.b, w1);     // W_j
        float Sy = fmaf(w0, A.c + A.d, w1);
        // inclusive scan: S_j = sum_{i<=j} (A^2)^(j-i) W_i
#pragma unroll
        for (int r = 0; r < 6; ++r) {
            int Dn = 1 << r;
            float ox = __shfl_up(Sx, Dn, 64);
            float oy = __shfl_up(Sy, Dn, 64);
            if (lane >= Dn) {
                float nx = Sx + fmaf(M[r].a, ox, M[r].b * oy);
                float ny = Sy + fmaf(M[r].c, ox, M[r].d * oy);
                Sx = nx; Sy = ny;
            }
        }
        float Ex = __shfl_up(Sx, 1, 64);
        float Ey = __shfl_up(Sy, 1, 64);
        if (lane == 0) { Ex = 0.f; Ey = 0.f; }
        // state before this lane's pair
        float pos = fmaf(P.a, s0v.x, fmaf(P.b, s0v.y, Ex));
        float vel = fmaf(P.c, s0v.x, fmaf(P.d, s0v.y, Ey));
        // re-walk 2 samples exactly
        float dir0 = h0 - pos;
        float acc0 = fmaf(k, dir0, fc.x);
        vel = (vel + acc0) * DAMP; pos += vel;
        float dir1 = h1 - pos;
        float acc1 = fmaf(k, dir1, fc.y);
        vel = (vel + acc1) * DAMP; pos += vel;
        disp2[c * 64 + lane] = make_float2(dir0, dir1);
        *(float2*)(&lR[d][2 * lane]) = make_float2(mm * acc0, mm * acc1);
        __syncthreads();
        if (tid < CLEN) {
            float s = 0.f;
#pragma unroll
            for (int dd = 0; dd < DD; ++dd) s += lR[dd][tid];
            out[REC_OFF + (size_t)bm * NS + c * CLEN + tid] = s;
        }
        __syncthreads();
    }
}

// ---------------- HF kernel: noise + combined 256-tap FIR + lf add ----------
// Grid 1024 = 256 (b,m) x 4 segments of 2048 outputs.
__global__ __launch_bounds__(256) void hf_kernel(
    const float* __restrict__ rec,
    const float* __restrict__ filters, const float* __restrict__ tfm,
    const float* __restrict__ bias,    const float* __restrict__ hf_gain,
    float* __restrict__ hf)
{
    __shared__ float up[FL + SEG];     // window [T0-256, T0+2048)
    __shared__ float gtap[FL];
    int bm  = blockIdx.x >> 2;
    int seg = blockIdx.x & 3;
    int b = bm >> 6;
    int m = bm & 63;
    int tx = threadIdx.x;
    int T0 = seg * SEG;

    float gs = 0.f;
#pragma unroll
    for (int f = 0; f < NF; ++f) {
        float mix = 0.f;
#pragma unroll
        for (int dd = 0; dd < DD; ++dd)
            mix = fmaf(bias[m * DD + dd], tfm[(m * DD + dd) * NF + f], mix);
        gs = fmaf(mix, filters[(b * NF + f) * FL + tx], gs);
    }
    gtap[tx] = gs;

    const float* rrow = rec + (size_t)bm * NS;
    for (int j = tx; j < FL + SEG; j += 256) {
        int t = T0 - FL + j;
        float v = 0.f;
        if (t >= 0) v = fabsf(rrow[t]) * jax_noise((unsigned)(bm * NS + t));
        up[j] = v;
    }
    __syncthreads();

    float gain = hf_gain[0];
    float* hrow = hf + (size_t)bm * NS;
    int t0 = tx * 8;                 // segment-local output base
    float acc[8] = {0, 0, 0, 0, 0, 0, 0, 0};
    float w[8];
#pragma unroll
    for (int j = 0; j < 8; ++j) w[j] = up[t0 + 1 + j];
#pragma unroll 8
    for (int s = 255; s >= 1; --s) {
        float gv = gtap[s];
#pragma unroll
        for (int j = 0; j < 8; ++j) acc[j] = fmaf(gv, w[j], acc[j]);
#pragma unroll
        for (int j = 0; j < 7; ++j) w[j] = w[j + 1];
        w[7] = up[FL + t0 + 8 - s];
    }
    float g0 = gtap[0];
#pragma unroll
    for (int j = 0; j < 8; ++j) acc[j] = fmaf(g0, w[j], acc[j]);
    float4 r0 = *(const float4*)(rrow + T0 + t0);
    float4 r1 = *(const float4*)(rrow + T0 + t0 + 4);
    float4 o0 = make_float4(fmaf(gain, acc[0], r0.x), fmaf(gain, acc[1], r0.y),
                            fmaf(gain, acc[2], r0.z), fmaf(gain, acc[3], r0.w));
    float4 o1 = make_float4(fmaf(gain, acc[4], r1.x), fmaf(gain, acc[5], r1.y),
                            fmaf(gain, acc[6], r1.z), fmaf(gain, acc[7], r1.w));
    *(float4*)(hrow + T0 + t0)     = o0;
    *(float4*)(hrow + T0 + t0 + 4) = o1;
}

extern "C" void kernel_launch(void* const* d_in, const int* in_sizes, int n_in,
                              void* d_out, int out_size, void* d_ws, size_t ws_size,
                              hipStream_t stream)
{
    const float* forces  = (const float*)d_in[0];
    const float* hm      = (const float*)d_in[1];
    const float* filters = (const float*)d_in[2];
    const float* home    = (const float*)d_in[3];
    const float* cs      = (const float*)d_in[4];
    const float* masses  = (const float*)d_in[5];
    const float* tens    = (const float*)d_in[6];
    const float* mics    = (const float*)d_in[7];
    const float* tfm     = (const float*)d_in[8];
    const float* bias    = (const float*)d_in[9];
    const float* gain    = (const float*)d_in[10];
    float* out = (float*)d_out;

    float2* q  = (float2*)d_ws;                 // 1 MiB
    float2* s0 = q + NCHAIN * CHUNKS;           // 1 MiB

    sim_phaseA<<<2048, 256, 0, stream>>>(forces, hm, home, cs, masses, tens, q);
    sim_phaseB<<<NCHAIN / 256, 256, 0, stream>>>(masses, tens, q, s0);
    sim_phaseC<<<BB * MM * 8, 512, 0, stream>>>(
        forces, hm, home, cs, masses, tens, mics, s0, out);
    hf_kernel<<<BB * MM * 4, 256, 0, stream>>>(
        out + REC_OFF, filters, tfm, bias, gain, out + HF_OFF);
}

// Round 5
// 113.508 us; speedup vs baseline: 2.7348x; 1.0199x over previous
//
#include <hip/hip_runtime.h>

// ---------------------------------------------------------------------------
// BetterGooLayer R5: 16-steps-per-lane wave-parallel scan.
// R4 post-mortem: phase A was DS-pipe-bound (12 wave-shuffles per 128 steps,
// FETCH~0 on L3-warm replays yet 55us). R5 amortizes cross-lane ops 8x:
// lane = (cg,sub): 8 lanes/chunk x 16 serial steps/lane, 8 chunks/wave.
//   phase A: 6 shuffles per 1024 steps (was 96).
//   phase C: 8 shuffles + LDS d-reduce per 1024 steps (was ~112 + barriers).
// Serial windows use the exact reference arithmetic; 128-step chunks still
// rebased from f64 phase-B states, so accuracy matches R3/R4 (absmax<=16).
// ---------------------------------------------------------------------------

#define NS    8192
#define BB    4
#define MM    64
#define DD    8
#define NF    8
#define FL    256
#define CHUNKS 64
#define NCHAIN (BB*MM*DD)   // 2048
#define DAMP  0.9998f
#define SEG   1024          // hf segment length

#define REC_OFF  0
#define DISP_OFF (BB*MM*NS)                 // 2097152
#define HF_OFF   (DISP_OFF + BB*MM*DD*NS)   // 18874368

struct Mat { float a, b, c, d; };   // [[a,b],[c,d]]
__device__ __forceinline__ Mat matmul(Mat x, Mat y) {
    Mat r;
    r.a = fmaf(x.a, y.a, x.b * y.c);
    r.b = fmaf(x.a, y.b, x.b * y.d);
    r.c = fmaf(x.c, y.a, x.d * y.c);
    r.d = fmaf(x.c, y.b, x.d * y.d);
    return r;
}

// ---------------- threefry2x32 (JAX, partitionable counters) ----------------
__device__ __forceinline__ unsigned rotl32(unsigned x, int r) {
    return (x << r) | (x >> (32 - r));
}
__device__ float jax_noise(unsigned idx) {
    const unsigned ks0 = 0u;
    const unsigned ks1 = 123u;
    const unsigned ks2 = 0x1BD11BDAu ^ 0u ^ 123u;
    unsigned x0 = 0u  + ks0;
    unsigned x1 = idx + ks1;
#define TF_RND(r) { x0 += x1; x1 = rotl32(x1, r); x1 ^= x0; }
    TF_RND(13) TF_RND(15) TF_RND(26) TF_RND(6)
    x0 += ks1; x1 += ks2 + 1u;
    TF_RND(17) TF_RND(29) TF_RND(16) TF_RND(24)
    x0 += ks2; x1 += ks0 + 2u;
    TF_RND(13) TF_RND(15) TF_RND(26) TF_RND(6)
    x0 += ks0; x1 += ks1 + 3u;
    TF_RND(17) TF_RND(29) TF_RND(16) TF_RND(24)
    x0 += ks1; x1 += ks2 + 4u;
    TF_RND(13) TF_RND(15) TF_RND(26) TF_RND(6)
    x0 += ks2; x1 += ks0 + 5u;
#undef TF_RND
    unsigned bits = x0 ^ x1;
    float u = __uint_as_float((bits >> 9) | 0x3f800000u) - 1.0f;  // [0,1)
    return fmaxf(-0.01f, u * 0.02f - 0.01f);
}

// one reference-exact sim step (forced recurrence)
#define SIMSTEP(ff, hh)                       \
    {                                         \
        float ht  = fmaf(hh, csm, hd);        \
        float dir = ht - pos;                 \
        float acc = fmaf(k, dir, ff);         \
        vel = (vel + acc) * DAMP;             \
        pos += vel;                           \
    }

// ---------------- Phase A: per-chunk forced response --------------------
// Wave covers 1024 steps (8 chunks). lane=(cg,sub): lane walks 16 steps from
// zero, weights by (A^16)^(7-sub), 3-round butterfly over sub -> q_chunk.
// 16384 waves = 4096 blocks x 4.
__global__ __launch_bounds__(256) void sim_phaseA(
    const float* __restrict__ forces, const float* __restrict__ hm,
    const float* __restrict__ home,   const float* __restrict__ cs,
    const float* __restrict__ masses, const float* __restrict__ tens,
    float2* __restrict__ qout)
{
    int wave = blockIdx.x * 4 + (threadIdx.x >> 6);
    int lane = threadIdx.x & 63;
    int ch  = wave >> 3;          // chain
    int grp = wave & 7;           // 1024-step group
    int sub = lane & 7;
    int cg  = lane >> 3;
    int m = (ch >> 3) & (MM - 1);
    int d = ch & (DD - 1);
    float k   = tens[m * DD + d] / masses[m];
    float csm = cs[m];
    float hd  = home[d];

    Mat A   = {1.f - DAMP * k, DAMP, -DAMP * k, DAMP};
    Mat A2  = matmul(A, A);
    Mat A4  = matmul(A2, A2);
    Mat A8  = matmul(A4, A4);
    Mat A16 = matmul(A8, A8);
    Mat A32 = matmul(A16, A16);
    Mat A64m = matmul(A32, A32);
    int e = 7 - sub;
    Mat P = {1.f, 0.f, 0.f, 1.f};
    if (e & 1) P = matmul(P, A16);
    if (e & 2) P = matmul(P, A32);
    if (e & 4) P = matmul(P, A64m);

    size_t base = (size_t)ch * NS + grp * 1024 + cg * 128 + sub * 16;
    float4 fq[4], hq[4];
#pragma unroll
    for (int q = 0; q < 4; ++q) {
        fq[q] = *(const float4*)(forces + base + q * 4);
        hq[q] = *(const float4*)(hm + base + q * 4);
    }
    const float* fr = (const float*)fq;
    const float* hr = (const float*)hq;

    float pos = 0.f, vel = 0.f;
#pragma unroll
    for (int i = 0; i < 16; ++i) SIMSTEP(fr[i], hr[i]);

    float qx = fmaf(P.a, pos, P.b * vel);
    float qy = fmaf(P.c, pos, P.d * vel);
#pragma unroll
    for (int o = 1; o < 8; o <<= 1) {
        qx += __shfl_xor(qx, o, 64);
        qy += __shfl_xor(qy, o, 64);
    }
    if (sub == 0)
        qout[ch * CHUNKS + grp * 8 + cg] = make_float2(qx, qy);
}

// ---------------- Phase B: per-chain f64 scan over chunks -------------------
__global__ __launch_bounds__(256) void sim_phaseB(
    const float* __restrict__ masses, const float* __restrict__ tens,
    const float2* __restrict__ q, float2* __restrict__ s0)
{
    int ch = blockIdx.x * 256 + threadIdx.x;
    if (ch >= NCHAIN) return;
    int m = (ch >> 3) & (MM - 1);
    int d = ch & (DD - 1);
    float kf = tens[m * DD + d] / masses[m];
    double k  = (double)kf;
    double dm = (double)DAMP;
    double p11 = 1.0 - dm * k, p12 = dm, p21 = -dm * k, p22 = dm;
    for (int i = 0; i < 7; ++i) {   // P = A^128
        double n11 = p11 * p11 + p12 * p21;
        double n12 = p11 * p12 + p12 * p22;
        double n21 = p21 * p11 + p22 * p21;
        double n22 = p21 * p12 + p22 * p22;
        p11 = n11; p12 = n12; p21 = n21; p22 = n22;
    }
    double sx = 0.0, sy = 0.0;
    for (int c = 0; c < CHUNKS; ++c) {
        s0[ch * CHUNKS + c] = make_float2((float)sx, (float)sy);
        float2 qc = q[ch * CHUNKS + c];
        double nx = p11 * sx + p12 * sy + (double)qc.x;
        double ny = p21 * sx + p22 * sy + (double)qc.y;
        sx = nx; sy = ny;
    }
}

// ---------------- Phase C: scan + re-walk, write disp/rec -------------------
// Block 512 = 8 waves (one per d of one bm); block covers one 1024-step group.
// Grid 2048 = 256 bm x 8 groups. One barrier per block.
__global__ __launch_bounds__(512) void sim_phaseC(
    const float* __restrict__ forces, const float* __restrict__ hm,
    const float* __restrict__ home,   const float* __restrict__ cs,
    const float* __restrict__ masses, const float* __restrict__ tens,
    const float* __restrict__ mics,   const float2* __restrict__ s0,
    float* __restrict__ out)
{
    __shared__ __align__(16) float lR[DD * 1028];   // stride 1028: d-read conflict-free
    int bm  = blockIdx.x >> 3;
    int grp = blockIdx.x & 7;
    int d    = threadIdx.x >> 6;
    int lane = threadIdx.x & 63;
    int sub = lane & 7;
    int cg  = lane >> 3;
    int m  = bm & (MM - 1);
    int ch = bm * DD + d;
    float ms  = masses[m];
    float k   = tens[m * DD + d] / ms;
    float csm = cs[m];
    float hd  = home[d];
    float mm  = ms * mics[m * DD + d];

    Mat A   = {1.f - DAMP * k, DAMP, -DAMP * k, DAMP};
    Mat A2  = matmul(A, A);
    Mat A4  = matmul(A2, A2);
    Mat A8  = matmul(A4, A4);
    Mat M0  = matmul(A8, A8);      // A^16
    Mat M1  = matmul(M0, M0);      // A^32
    Mat M2  = matmul(M1, M1);      // A^64
    Mat P = {1.f, 0.f, 0.f, 1.f};  // (A^16)^sub
    if (sub & 1) P = matmul(P, M0);
    if (sub & 2) P = matmul(P, M1);
    if (sub & 4) P = matmul(P, M2);

    int c = grp * 8 + cg;
    float2 s0v = s0[ch * CHUNKS + c];
    size_t base = (size_t)ch * NS + grp * 1024 + cg * 128 + sub * 16;
    float4 fq[4], hq[4];
#pragma unroll
    for (int q = 0; q < 4; ++q) {
        fq[q] = *(const float4*)(forces + base + q * 4);
        hq[q] = *(const float4*)(hm + base + q * 4);
    }
    const float* fr = (const float*)fq;
    const float* hr = (const float*)hq;

    // pass 1: forced response of this lane's 16-step window
    float pos = 0.f, vel = 0.f;
#pragma unroll
    for (int i = 0; i < 16; ++i) SIMSTEP(fr[i], hr[i]);
    float Wx = pos, Wy = vel;

    // inclusive Kogge-Stone scan within 8-lane groups (matrix-weighted)
    {
        float ox, oy;
        ox = __shfl_up(Wx, 1, 64); oy = __shfl_up(Wy, 1, 64);
        if (sub >= 1) { float nx = Wx + fmaf(M0.a, ox, M0.b * oy);
                        float ny = Wy + fmaf(M0.c, ox, M0.d * oy);
                        Wx = nx; Wy = ny; }
        ox = __shfl_up(Wx, 2, 64); oy = __shfl_up(Wy, 2, 64);
        if (sub >= 2) { float nx = Wx + fmaf(M1.a, ox, M1.b * oy);
                        float ny = Wy + fmaf(M1.c, ox, M1.d * oy);
                        Wx = nx; Wy = ny; }
        ox = __shfl_up(Wx, 4, 64); oy = __shfl_up(Wy, 4, 64);
        if (sub >= 4) { float nx = Wx + fmaf(M2.a, ox, M2.b * oy);
                        float ny = Wy + fmaf(M2.c, ox, M2.d * oy);
                        Wx = nx; Wy = ny; }
    }
    float Ex = __shfl_up(Wx, 1, 64);
    float Ey = __shfl_up(Wy, 1, 64);
    if (sub == 0) { Ex = 0.f; Ey = 0.f; }

    // start state of this window, then re-walk exactly
    pos = fmaf(P.a, s0v.x, fmaf(P.b, s0v.y, Ex));
    vel = fmaf(P.c, s0v.x, fmaf(P.d, s0v.y, Ey));

    int a0  = cg * 128 + sub * 16;
    int swz = (cg & 3) << 2;
#pragma unroll
    for (int q = 0; q < 4; ++q) {
        float dv[4], rv[4];
#pragma unroll
        for (int i = 0; i < 4; ++i) {
            float ff = fr[q * 4 + i], hh = hr[q * 4 + i];
            float ht  = fmaf(hh, csm, hd);
            float dir = ht - pos;
            float acc = fmaf(k, dir, ff);
            vel = (vel + acc) * DAMP;
            pos += vel;
            dv[i] = dir;
            rv[i] = mm * acc;
        }
        *(float4*)(out + DISP_OFF + base + q * 4) =
            make_float4(dv[0], dv[1], dv[2], dv[3]);
        *(float4*)(&lR[d * 1028 + ((a0 + q * 4) ^ swz)]) =
            make_float4(rv[0], rv[1], rv[2], rv[3]);
    }
    __syncthreads();

    // d-reduce: 512 threads x 2 outputs
    int t0  = threadIdx.x * 2;
    int cgr = t0 >> 7;
    int t0s = t0 ^ ((cgr & 3) << 2);
    float sx = 0.f, sy = 0.f;
#pragma unroll
    for (int dd2 = 0; dd2 < DD; ++dd2) {
        float2 v = *(const float2*)(&lR[dd2 * 1028 + t0s]);
        sx += v.x; sy += v.y;
    }
    *(float2*)(out + REC_OFF + (size_t)bm * NS + grp * 1024 + t0) =
        make_float2(sx, sy);
}

// ---------------- HF kernel: noise + combined 256-tap FIR + lf add ----------
// Grid 2048 = 256 (b,m) x 8 segments of 1024 outputs.
__global__ __launch_bounds__(256) void hf_kernel(
    const float* __restrict__ rec,
    const float* __restrict__ filters, const float* __restrict__ tfm,
    const float* __restrict__ bias,    const float* __restrict__ hf_gain,
    float* __restrict__ hf)
{
    __shared__ float up[FL + SEG];     // window [T0-256, T0+1024)
    __shared__ float gtap[FL];
    int bm  = blockIdx.x >> 3;
    int seg = blockIdx.x & 7;
    int b = bm >> 6;
    int m = bm & 63;
    int tx = threadIdx.x;
    int T0 = seg * SEG;

    float gs = 0.f;
#pragma unroll
    for (int f = 0; f < NF; ++f) {
        float mix = 0.f;
#pragma unroll
        for (int dd = 0; dd < DD; ++dd)
            mix = fmaf(bias[m * DD + dd], tfm[(m * DD + dd) * NF + f], mix);
        gs = fmaf(mix, filters[(b * NF + f) * FL + tx], gs);
    }
    gtap[tx] = gs;

    const float* rrow = rec + (size_t)bm * NS;
    for (int j = tx; j < FL + SEG; j += 256) {
        int t = T0 - FL + j;
        float v = 0.f;
        if (t >= 0) v = fabsf(rrow[t]) * jax_noise((unsigned)(bm * NS + t));
        up[j] = v;
    }
    __syncthreads();

    float gain = hf_gain[0];
    float* hrow = hf + (size_t)bm * NS;
    int t0 = tx * 4;                 // segment-local output base
    float acc[4] = {0, 0, 0, 0};
    float w[4];
#pragma unroll
    for (int j = 0; j < 4; ++j) w[j] = up[t0 + 1 + j];
#pragma unroll 4
    for (int s = 255; s >= 1; --s) {
        float gv = gtap[s];
#pragma unroll
        for (int j = 0; j < 4; ++j) acc[j] = fmaf(gv, w[j], acc[j]);
#pragma unroll
        for (int j = 0; j < 3; ++j) w[j] = w[j + 1];
        w[3] = up[FL + t0 + 4 - s];
    }
    float g0 = gtap[0];
#pragma unroll
    for (int j = 0; j < 4; ++j) acc[j] = fmaf(g0, w[j], acc[j]);
    float4 r0 = *(const float4*)(rrow + T0 + t0);
    float4 o0 = make_float4(fmaf(gain, acc[0], r0.x), fmaf(gain, acc[1], r0.y),
                            fmaf(gain, acc[2], r0.z), fmaf(gain, acc[3], r0.w));
    *(float4*)(hrow + T0 + t0) = o0;
}

extern "C" void kernel_launch(void* const* d_in, const int* in_sizes, int n_in,
                              void* d_out, int out_size, void* d_ws, size_t ws_size,
                              hipStream_t stream)
{
    const float* forces  = (const float*)d_in[0];
    const float* hm      = (const float*)d_in[1];
    const float* filters = (const float*)d_in[2];
    const float* home    = (const float*)d_in[3];
    const float* cs      = (const float*)d_in[4];
    const float* masses  = (const float*)d_in[5];
    const float* tens    = (const float*)d_in[6];
    const float* mics    = (const float*)d_in[7];
    const float* tfm     = (const float*)d_in[8];
    const float* bias    = (const float*)d_in[9];
    const float* gain    = (const float*)d_in[10];
    float* out = (float*)d_out;

    float2* q  = (float2*)d_ws;                 // 1 MiB
    float2* s0 = q + NCHAIN * CHUNKS;           // 1 MiB

    sim_phaseA<<<4096, 256, 0, stream>>>(forces, hm, home, cs, masses, tens, q);
    sim_phaseB<<<NCHAIN / 256, 256, 0, stream>>>(masses, tens, q, s0);
    sim_phaseC<<<BB * MM * 8, 512, 0, stream>>>(
        forces, hm, home, cs, masses, tens, mics, s0, out);
    hf_kernel<<<BB * MM * 8, 256, 0, stream>>>(
        out + REC_OFF, filters, tfm, bias, gain, out + HF_OFF);
}

// Round 6
// 102.968 us; speedup vs baseline: 3.0148x; 1.1024x over previous
//
#include <hip/hip_runtime.h>

// ---------------------------------------------------------------------------
// BetterGooLayer R6: hf FIR rewrite (R5 showed hf ~48.7us, LDS-bound).
//   - up[] stored with +1-per-32-float pad (idx + idx>>5): the stride-8 window
//     read becomes bank-conflict-free (2-way aliasing = free).
//   - 8 consecutive outputs/thread, register sliding window, full unroll:
//     1 LDS read per 8 FMAs (was 2 per 4, one 8-way-conflicted).
//   - SEG=2048, 4 segments/row -> 1024 blocks (4/CU, 16 waves/CU).
// Sim kernels unchanged from R5 (absmax 8.0 passing).
// ---------------------------------------------------------------------------

#define NS    8192
#define BB    4
#define MM    64
#define DD    8
#define NF    8
#define FL    256
#define CHUNKS 64
#define NCHAIN (BB*MM*DD)   // 2048
#define DAMP  0.9998f
#define SEG   2048          // hf segment length

#define REC_OFF  0
#define DISP_OFF (BB*MM*NS)                 // 2097152
#define HF_OFF   (DISP_OFF + BB*MM*DD*NS)   // 18874368

// LDS swizzle: +1 float pad per 32 floats (spreads stride-8 reads over banks)
#define SW(i) ((i) + ((i) >> 5))

struct Mat { float a, b, c, d; };   // [[a,b],[c,d]]
__device__ __forceinline__ Mat matmul(Mat x, Mat y) {
    Mat r;
    r.a = fmaf(x.a, y.a, x.b * y.c);
    r.b = fmaf(x.a, y.b, x.b * y.d);
    r.c = fmaf(x.c, y.a, x.d * y.c);
    r.d = fmaf(x.c, y.b, x.d * y.d);
    return r;
}

// ---------------- threefry2x32 (JAX, partitionable counters) ----------------
__device__ __forceinline__ unsigned rotl32(unsigned x, int r) {
    return (x << r) | (x >> (32 - r));
}
__device__ float jax_noise(unsigned idx) {
    const unsigned ks0 = 0u;
    const unsigned ks1 = 123u;
    const unsigned ks2 = 0x1BD11BDAu ^ 0u ^ 123u;
    unsigned x0 = 0u  + ks0;
    unsigned x1 = idx + ks1;
#define TF_RND(r) { x0 += x1; x1 = rotl32(x1, r); x1 ^= x0; }
    TF_RND(13) TF_RND(15) TF_RND(26) TF_RND(6)
    x0 += ks1; x1 += ks2 + 1u;
    TF_RND(17) TF_RND(29) TF_RND(16) TF_RND(24)
    x0 += ks2; x1 += ks0 + 2u;
    TF_RND(13) TF_RND(15) TF_RND(26) TF_RND(6)
    x0 += ks0; x1 += ks1 + 3u;
    TF_RND(17) TF_RND(29) TF_RND(16) TF_RND(24)
    x0 += ks1; x1 += ks2 + 4u;
    TF_RND(13) TF_RND(15) TF_RND(26) TF_RND(6)
    x0 += ks2; x1 += ks0 + 5u;
#undef TF_RND
    unsigned bits = x0 ^ x1;
    float u = __uint_as_float((bits >> 9) | 0x3f800000u) - 1.0f;  // [0,1)
    return fmaxf(-0.01f, u * 0.02f - 0.01f);
}

// one reference-exact sim step (forced recurrence)
#define SIMSTEP(ff, hh)                       \
    {                                         \
        float ht  = fmaf(hh, csm, hd);        \
        float dir = ht - pos;                 \
        float acc = fmaf(k, dir, ff);         \
        vel = (vel + acc) * DAMP;             \
        pos += vel;                           \
    }

// ---------------- Phase A: per-chunk forced response --------------------
__global__ __launch_bounds__(256) void sim_phaseA(
    const float* __restrict__ forces, const float* __restrict__ hm,
    const float* __restrict__ home,   const float* __restrict__ cs,
    const float* __restrict__ masses, const float* __restrict__ tens,
    float2* __restrict__ qout)
{
    int wave = blockIdx.x * 4 + (threadIdx.x >> 6);
    int lane = threadIdx.x & 63;
    int ch  = wave >> 3;          // chain
    int grp = wave & 7;           // 1024-step group
    int sub = lane & 7;
    int cg  = lane >> 3;
    int m = (ch >> 3) & (MM - 1);
    int d = ch & (DD - 1);
    float k   = tens[m * DD + d] / masses[m];
    float csm = cs[m];
    float hd  = home[d];

    Mat A   = {1.f - DAMP * k, DAMP, -DAMP * k, DAMP};
    Mat A2  = matmul(A, A);
    Mat A4  = matmul(A2, A2);
    Mat A8  = matmul(A4, A4);
    Mat A16 = matmul(A8, A8);
    Mat A32 = matmul(A16, A16);
    Mat A64m = matmul(A32, A32);
    int e = 7 - sub;
    Mat P = {1.f, 0.f, 0.f, 1.f};
    if (e & 1) P = matmul(P, A16);
    if (e & 2) P = matmul(P, A32);
    if (e & 4) P = matmul(P, A64m);

    size_t base = (size_t)ch * NS + grp * 1024 + cg * 128 + sub * 16;
    float4 fq[4], hq[4];
#pragma unroll
    for (int q = 0; q < 4; ++q) {
        fq[q] = *(const float4*)(forces + base + q * 4);
        hq[q] = *(const float4*)(hm + base + q * 4);
    }
    const float* fr = (const float*)fq;
    const float* hr = (const float*)hq;

    float pos = 0.f, vel = 0.f;
#pragma unroll
    for (int i = 0; i < 16; ++i) SIMSTEP(fr[i], hr[i]);

    float qx = fmaf(P.a, pos, P.b * vel);
    float qy = fmaf(P.c, pos, P.d * vel);
#pragma unroll
    for (int o = 1; o < 8; o <<= 1) {
        qx += __shfl_xor(qx, o, 64);
        qy += __shfl_xor(qy, o, 64);
    }
    if (sub == 0)
        qout[ch * CHUNKS + grp * 8 + cg] = make_float2(qx, qy);
}

// ---------------- Phase B: per-chain f64 scan over chunks -------------------
__global__ __launch_bounds__(256) void sim_phaseB(
    const float* __restrict__ masses, const float* __restrict__ tens,
    const float2* __restrict__ q, float2* __restrict__ s0)
{
    int ch = blockIdx.x * 256 + threadIdx.x;
    if (ch >= NCHAIN) return;
    int m = (ch >> 3) & (MM - 1);
    int d = ch & (DD - 1);
    float kf = tens[m * DD + d] / masses[m];
    double k  = (double)kf;
    double dm = (double)DAMP;
    double p11 = 1.0 - dm * k, p12 = dm, p21 = -dm * k, p22 = dm;
    for (int i = 0; i < 7; ++i) {   // P = A^128
        double n11 = p11 * p11 + p12 * p21;
        double n12 = p11 * p12 + p12 * p22;
        double n21 = p21 * p11 + p22 * p21;
        double n22 = p21 * p12 + p22 * p22;
        p11 = n11; p12 = n12; p21 = n21; p22 = n22;
    }
    double sx = 0.0, sy = 0.0;
    for (int c = 0; c < CHUNKS; ++c) {
        s0[ch * CHUNKS + c] = make_float2((float)sx, (float)sy);
        float2 qc = q[ch * CHUNKS + c];
        double nx = p11 * sx + p12 * sy + (double)qc.x;
        double ny = p21 * sx + p22 * sy + (double)qc.y;
        sx = nx; sy = ny;
    }
}

// ---------------- Phase C: scan + re-walk, write disp/rec -------------------
__global__ __launch_bounds__(512) void sim_phaseC(
    const float* __restrict__ forces, const float* __restrict__ hm,
    const float* __restrict__ home,   const float* __restrict__ cs,
    const float* __restrict__ masses, const float* __restrict__ tens,
    const float* __restrict__ mics,   const float2* __restrict__ s0,
    float* __restrict__ out)
{
    __shared__ __align__(16) float lR[DD * 1028];
    int bm  = blockIdx.x >> 3;
    int grp = blockIdx.x & 7;
    int d    = threadIdx.x >> 6;
    int lane = threadIdx.x & 63;
    int sub = lane & 7;
    int cg  = lane >> 3;
    int m  = bm & (MM - 1);
    int ch = bm * DD + d;
    float ms  = masses[m];
    float k   = tens[m * DD + d] / ms;
    float csm = cs[m];
    float hd  = home[d];
    float mm  = ms * mics[m * DD + d];

    Mat A   = {1.f - DAMP * k, DAMP, -DAMP * k, DAMP};
    Mat A2  = matmul(A, A);
    Mat A4  = matmul(A2, A2);
    Mat A8  = matmul(A4, A4);
    Mat M0  = matmul(A8, A8);      // A^16
    Mat M1  = matmul(M0, M0);      // A^32
    Mat M2  = matmul(M1, M1);      // A^64
    Mat P = {1.f, 0.f, 0.f, 1.f};  // (A^16)^sub
    if (sub & 1) P = matmul(P, M0);
    if (sub & 2) P = matmul(P, M1);
    if (sub & 4) P = matmul(P, M2);

    int c = grp * 8 + cg;
    float2 s0v = s0[ch * CHUNKS + c];
    size_t base = (size_t)ch * NS + grp * 1024 + cg * 128 + sub * 16;
    float4 fq[4], hq[4];
#pragma unroll
    for (int q = 0; q < 4; ++q) {
        fq[q] = *(const float4*)(forces + base + q * 4);
        hq[q] = *(const float4*)(hm + base + q * 4);
    }
    const float* fr = (const float*)fq;
    const float* hr = (const float*)hq;

    // pass 1: forced response of this lane's 16-step window
    float pos = 0.f, vel = 0.f;
#pragma unroll
    for (int i = 0; i < 16; ++i) SIMSTEP(fr[i], hr[i]);
    float Wx = pos, Wy = vel;

    // inclusive Kogge-Stone scan within 8-lane groups (matrix-weighted)
    {
        float ox, oy;
        ox = __shfl_up(Wx, 1, 64); oy = __shfl_up(Wy, 1, 64);
        if (sub >= 1) { float nx = Wx + fmaf(M0.a, ox, M0.b * oy);
                        float ny = Wy + fmaf(M0.c, ox, M0.d * oy);
                        Wx = nx; Wy = ny; }
        ox = __shfl_up(Wx, 2, 64); oy = __shfl_up(Wy, 2, 64);
        if (sub >= 2) { float nx = Wx + fmaf(M1.a, ox, M1.b * oy);
                        float ny = Wy + fmaf(M1.c, ox, M1.d * oy);
                        Wx = nx; Wy = ny; }
        ox = __shfl_up(Wx, 4, 64); oy = __shfl_up(Wy, 4, 64);
        if (sub >= 4) { float nx = Wx + fmaf(M2.a, ox, M2.b * oy);
                        float ny = Wy + fmaf(M2.c, ox, M2.d * oy);
                        Wx = nx; Wy = ny; }
    }
    float Ex = __shfl_up(Wx, 1, 64);
    float Ey = __shfl_up(Wy, 1, 64);
    if (sub == 0) { Ex = 0.f; Ey = 0.f; }

    pos = fmaf(P.a, s0v.x, fmaf(P.b, s0v.y, Ex));
    vel = fmaf(P.c, s0v.x, fmaf(P.d, s0v.y, Ey));

    int a0  = cg * 128 + sub * 16;
    int swz = (cg & 3) << 2;
#pragma unroll
    for (int q = 0; q < 4; ++q) {
        float dv[4], rv[4];
#pragma unroll
        for (int i = 0; i < 4; ++i) {
            float ff = fr[q * 4 + i], hh = hr[q * 4 + i];
            float ht  = fmaf(hh, csm, hd);
            float dir = ht - pos;
            float acc = fmaf(k, dir, ff);
            vel = (vel + acc) * DAMP;
            pos += vel;
            dv[i] = dir;
            rv[i] = mm * acc;
        }
        *(float4*)(out + DISP_OFF + base + q * 4) =
            make_float4(dv[0], dv[1], dv[2], dv[3]);
        *(float4*)(&lR[d * 1028 + ((a0 + q * 4) ^ swz)]) =
            make_float4(rv[0], rv[1], rv[2], rv[3]);
    }
    __syncthreads();

    int t0  = threadIdx.x * 2;
    int cgr = t0 >> 7;
    int t0s = t0 ^ ((cgr & 3) << 2);
    float sx = 0.f, sy = 0.f;
#pragma unroll
    for (int dd2 = 0; dd2 < DD; ++dd2) {
        float2 v = *(const float2*)(&lR[dd2 * 1028 + t0s]);
        sx += v.x; sy += v.y;
    }
    *(float2*)(out + REC_OFF + (size_t)bm * NS + grp * 1024 + t0) =
        make_float2(sx, sy);
}

// ---------------- HF kernel: noise + combined 256-tap FIR + lf add ----------
// Grid 1024 = 256 (b,m) x 4 segments of 2048 outputs. 8 outputs/thread,
// swizzled up[] (conflict-free window reads), register sliding window.
__global__ __launch_bounds__(256) void hf_kernel(
    const float* __restrict__ rec,
    const float* __restrict__ filters, const float* __restrict__ tfm,
    const float* __restrict__ bias,    const float* __restrict__ hf_gain,
    float* __restrict__ hf)
{
    __shared__ float up[SW(FL + SEG) + 8];   // swizzled window [T0-256, T0+2048)
    __shared__ float gtap[FL];
    int bm  = blockIdx.x >> 2;
    int seg = blockIdx.x & 3;
    int b = bm >> 6;
    int m = bm & 63;
    int tx = threadIdx.x;
    int T0 = seg * SEG;

    float gs = 0.f;
#pragma unroll
    for (int f = 0; f < NF; ++f) {
        float mix = 0.f;
#pragma unroll
        for (int dd = 0; dd < DD; ++dd)
            mix = fmaf(bias[m * DD + dd], tfm[(m * DD + dd) * NF + f], mix);
        gs = fmaf(mix, filters[(b * NF + f) * FL + tx], gs);
    }
    gtap[tx] = gs;

    const float* rrow = rec + (size_t)bm * NS;
    for (int j = tx; j < FL + SEG; j += 256) {
        int t = T0 - FL + j;
        float v = 0.f;
        if (t >= 0) v = fabsf(rrow[t]) * jax_noise((unsigned)(bm * NS + t));
        up[SW(j)] = v;
    }
    __syncthreads();

    float gain = hf_gain[0];
    float* hrow = hf + (size_t)bm * NS;
    int t0 = tx * 8;                 // segment-local output base
    float acc[8] = {0, 0, 0, 0, 0, 0, 0, 0};
    float w[8];
#pragma unroll
    for (int j = 0; j < 8; ++j) w[j] = up[SW(t0 + 1 + j)];
#pragma unroll 8
    for (int s = 255; s >= 1; --s) {
        float gv = gtap[s];
#pragma unroll
        for (int j = 0; j < 8; ++j) acc[j] = fmaf(gv, w[j], acc[j]);
#pragma unroll
        for (int j = 0; j < 7; ++j) w[j] = w[j + 1];
        w[7] = up[SW(FL + t0 + 8 - s)];
    }
    float g0 = gtap[0];
#pragma unroll
    for (int j = 0; j < 8; ++j) acc[j] = fmaf(g0, w[j], acc[j]);
    float4 r0 = *(const float4*)(rrow + T0 + t0);
    float4 r1 = *(const float4*)(rrow + T0 + t0 + 4);
    float4 o0 = make_float4(fmaf(gain, acc[0], r0.x), fmaf(gain, acc[1], r0.y),
                            fmaf(gain, acc[2], r0.z), fmaf(gain, acc[3], r0.w));
    float4 o1 = make_float4(fmaf(gain, acc[4], r1.x), fmaf(gain, acc[5], r1.y),
                            fmaf(gain, acc[6], r1.z), fmaf(gain, acc[7], r1.w));
    *(float4*)(hrow + T0 + t0)     = o0;
    *(float4*)(hrow + T0 + t0 + 4) = o1;
}

extern "C" void kernel_launch(void* const* d_in, const int* in_sizes, int n_in,
                              void* d_out, int out_size, void* d_ws, size_t ws_size,
                              hipStream_t stream)
{
    const float* forces  = (const float*)d_in[0];
    const float* hm      = (const float*)d_in[1];
    const float* filters = (const float*)d_in[2];
    const float* home    = (const float*)d_in[3];
    const float* cs      = (const float*)d_in[4];
    const float* masses  = (const float*)d_in[5];
    const float* tens    = (const float*)d_in[6];
    const float* mics    = (const float*)d_in[7];
    const float* tfm     = (const float*)d_in[8];
    const float* bias    = (const float*)d_in[9];
    const float* gain    = (const float*)d_in[10];
    float* out = (float*)d_out;

    float2* q  = (float2*)d_ws;                 // 1 MiB
    float2* s0 = q + NCHAIN * CHUNKS;           // 1 MiB

    sim_phaseA<<<4096, 256, 0, stream>>>(forces, hm, home, cs, masses, tens, q);
    sim_phaseB<<<NCHAIN / 256, 256, 0, stream>>>(masses, tens, q, s0);
    sim_phaseC<<<BB * MM * 8, 512, 0, stream>>>(
        forces, hm, home, cs, masses, tens, mics, s0, out);
    hf_kernel<<<BB * MM * 4, 256, 0, stream>>>(
        out + REC_OFF, filters, tfm, bias, gain, out + HF_OFF);
}

// Round 7
// 101.278 us; speedup vs baseline: 3.0651x; 1.0167x over previous
//
#include <hip/hip_runtime.h>

// ---------------------------------------------------------------------------
// BetterGooLayer R7: transaction-efficient I/O via in-wave LDS transpose.
// R6 post-mortem: phaseA 49.8us at VALUBusy 10% / HBM 17% -> TA-transaction
// bound (64B-stride lanes: 512 cache-line requests/wave). R7 loads/stores
// lane-consecutive (1KB per instr) and transposes through LDS (stride-20
// window layout: read quads (5w+q)&7 hit all 8 bank-quads).
// Scan math, lane->window mapping, f64 rebase, exact phaseC walk: unchanged.
// ---------------------------------------------------------------------------

#define NS    8192
#define BB    4
#define MM    64
#define DD    8
#define NF    8
#define FL    256
#define CHUNKS 64
#define NCHAIN (BB*MM*DD)   // 2048
#define DAMP  0.9998f
#define SEG   2048          // hf segment length

#define REC_OFF  0
#define DISP_OFF (BB*MM*NS)                 // 2097152
#define HF_OFF   (DISP_OFF + BB*MM*DD*NS)   // 18874368

// hf up[] swizzle: +1 float pad per 32 (stride-8 window reads conflict-free)
#define SW(i) ((i) + ((i) >> 5))
// phaseC rv swizzle: granule-XOR spreads all 8 bank-quads
#define P_SWZ(p) (((p) & ~15) | (((((p) >> 2) ^ ((p) >> 5)) & 3) << 2) | ((p) & 3))

struct Mat { float a, b, c, d; };   // [[a,b],[c,d]]
__device__ __forceinline__ Mat matmul(Mat x, Mat y) {
    Mat r;
    r.a = fmaf(x.a, y.a, x.b * y.c);
    r.b = fmaf(x.a, y.b, x.b * y.d);
    r.c = fmaf(x.c, y.a, x.d * y.c);
    r.d = fmaf(x.c, y.b, x.d * y.d);
    return r;
}

// ---------------- threefry2x32 (JAX, partitionable counters) ----------------
__device__ __forceinline__ unsigned rotl32(unsigned x, int r) {
    return (x << r) | (x >> (32 - r));
}
__device__ float jax_noise(unsigned idx) {
    const unsigned ks0 = 0u;
    const unsigned ks1 = 123u;
    const unsigned ks2 = 0x1BD11BDAu ^ 0u ^ 123u;
    unsigned x0 = 0u  + ks0;
    unsigned x1 = idx + ks1;
#define TF_RND(r) { x0 += x1; x1 = rotl32(x1, r); x1 ^= x0; }
    TF_RND(13) TF_RND(15) TF_RND(26) TF_RND(6)
    x0 += ks1; x1 += ks2 + 1u;
    TF_RND(17) TF_RND(29) TF_RND(16) TF_RND(24)
    x0 += ks2; x1 += ks0 + 2u;
    TF_RND(13) TF_RND(15) TF_RND(26) TF_RND(6)
    x0 += ks0; x1 += ks1 + 3u;
    TF_RND(17) TF_RND(29) TF_RND(16) TF_RND(24)
    x0 += ks1; x1 += ks2 + 4u;
    TF_RND(13) TF_RND(15) TF_RND(26) TF_RND(6)
    x0 += ks2; x1 += ks0 + 5u;
#undef TF_RND
    unsigned bits = x0 ^ x1;
    float u = __uint_as_float((bits >> 9) | 0x3f800000u) - 1.0f;  // [0,1)
    return fmaxf(-0.01f, u * 0.02f - 0.01f);
}

// ---------------- Phase A: per-chunk forced response ------------------------
// Wave covers 1024 steps; lane w owns window [w*16, w*16+16). Coalesced loads
// + LDS transpose; u_t = f + k*(h*cs+home) combined (rebased by f64 phase B).
__global__ __launch_bounds__(256, 8) void sim_phaseA(
    const float* __restrict__ forces, const float* __restrict__ hm,
    const float* __restrict__ home,   const float* __restrict__ cs,
    const float* __restrict__ masses, const float* __restrict__ tens,
    float2* __restrict__ qout)
{
    __shared__ __align__(16) float sbuf[4][64 * 20];
    int wl   = threadIdx.x >> 6;
    int lane = threadIdx.x & 63;
    int wave = blockIdx.x * 4 + wl;
    int ch  = wave >> 3;
    int grp = wave & 7;
    int sub = lane & 7;
    int cg  = lane >> 3;
    int m = (ch >> 3) & (MM - 1);
    int d = ch & (DD - 1);
    float k   = tens[m * DD + d] / masses[m];
    float csm = cs[m];
    float hd  = home[d];

    size_t gbase = (size_t)ch * NS + grp * 1024;
    float* sb = sbuf[wl];
    int wp = (lane >> 2) * 20 + (lane & 3) * 4;   // write pos for instr i=0

    // issue all 8 coalesced loads up front
    float4 f0 = *(const float4*)(forces + gbase + 0 * 256 + 4 * lane);
    float4 f1 = *(const float4*)(forces + gbase + 1 * 256 + 4 * lane);
    float4 f2 = *(const float4*)(forces + gbase + 2 * 256 + 4 * lane);
    float4 f3 = *(const float4*)(forces + gbase + 3 * 256 + 4 * lane);
    float4 h0 = *(const float4*)(hm + gbase + 0 * 256 + 4 * lane);
    float4 h1 = *(const float4*)(hm + gbase + 1 * 256 + 4 * lane);
    float4 h2 = *(const float4*)(hm + gbase + 2 * 256 + 4 * lane);
    float4 h3 = *(const float4*)(hm + gbase + 3 * 256 + 4 * lane);

    // transpose forces
    *(float4*)(sb + wp + 0 * 16 * 20) = f0;
    *(float4*)(sb + wp + 1 * 16 * 20) = f1;
    *(float4*)(sb + wp + 2 * 16 * 20) = f2;
    *(float4*)(sb + wp + 3 * 16 * 20) = f3;
    __syncthreads();
    float4 uq[4];
#pragma unroll
    for (int q = 0; q < 4; ++q)
        uq[q] = *(const float4*)(sb + lane * 20 + 4 * q);
    __syncthreads();
    // transpose hm, combine into u = fmaf(k, h*csm+hd, f)
    *(float4*)(sb + wp + 0 * 16 * 20) = h0;
    *(float4*)(sb + wp + 1 * 16 * 20) = h1;
    *(float4*)(sb + wp + 2 * 16 * 20) = h2;
    *(float4*)(sb + wp + 3 * 16 * 20) = h3;
    __syncthreads();
#pragma unroll
    for (int q = 0; q < 4; ++q) {
        float4 hv = *(const float4*)(sb + lane * 20 + 4 * q);
        uq[q].x = fmaf(k, fmaf(hv.x, csm, hd), uq[q].x);
        uq[q].y = fmaf(k, fmaf(hv.y, csm, hd), uq[q].y);
        uq[q].z = fmaf(k, fmaf(hv.z, csm, hd), uq[q].z);
        uq[q].w = fmaf(k, fmaf(hv.w, csm, hd), uq[q].w);
    }

    // zero-state 16-step walk: acc = u - k*pos
    const float* ur = (const float*)uq;
    float pos = 0.f, vel = 0.f;
#pragma unroll
    for (int i = 0; i < 16; ++i) {
        float acc = fmaf(-k, pos, ur[i]);
        vel = (vel + acc) * DAMP;
        pos += vel;
    }

    // weight by (A^16)^(7-sub), butterfly over sub
    Mat A   = {1.f - DAMP * k, DAMP, -DAMP * k, DAMP};
    Mat A2  = matmul(A, A);
    Mat A4  = matmul(A2, A2);
    Mat A8  = matmul(A4, A4);
    Mat A16 = matmul(A8, A8);
    Mat A32 = matmul(A16, A16);
    Mat A64m = matmul(A32, A32);
    int e = 7 - sub;
    Mat P = {1.f, 0.f, 0.f, 1.f};
    if (e & 1) P = matmul(P, A16);
    if (e & 2) P = matmul(P, A32);
    if (e & 4) P = matmul(P, A64m);
    float qx = fmaf(P.a, pos, P.b * vel);
    float qy = fmaf(P.c, pos, P.d * vel);
#pragma unroll
    for (int o = 1; o < 8; o <<= 1) {
        qx += __shfl_xor(qx, o, 64);
        qy += __shfl_xor(qy, o, 64);
    }
    if (sub == 0)
        qout[ch * CHUNKS + grp * 8 + cg] = make_float2(qx, qy);
}

// ---------------- Phase B: per-chain f64 scan over chunks -------------------
__global__ __launch_bounds__(256) void sim_phaseB(
    const float* __restrict__ masses, const float* __restrict__ tens,
    const float2* __restrict__ q, float2* __restrict__ s0)
{
    int ch = blockIdx.x * 256 + threadIdx.x;
    if (ch >= NCHAIN) return;
    int m = (ch >> 3) & (MM - 1);
    int d = ch & (DD - 1);
    float kf = tens[m * DD + d] / masses[m];
    double k  = (double)kf;
    double dm = (double)DAMP;
    double p11 = 1.0 - dm * k, p12 = dm, p21 = -dm * k, p22 = dm;
    for (int i = 0; i < 7; ++i) {   // P = A^128
        double n11 = p11 * p11 + p12 * p21;
        double n12 = p11 * p12 + p12 * p22;
        double n21 = p21 * p11 + p22 * p21;
        double n22 = p21 * p12 + p22 * p22;
        p11 = n11; p12 = n12; p21 = n21; p22 = n22;
    }
    double sx = 0.0, sy = 0.0;
    for (int c = 0; c < CHUNKS; ++c) {
        s0[ch * CHUNKS + c] = make_float2((float)sx, (float)sy);
        float2 qc = q[ch * CHUNKS + c];
        double nx = p11 * sx + p12 * sy + (double)qc.x;
        double ny = p21 * sx + p22 * sy + (double)qc.y;
        sx = nx; sy = ny;
    }
}

// ---------------- Phase C: scan + re-walk, write disp/rec -------------------
// Block 512 = 8 waves (one per d); block covers (bm, 1024-step group).
__global__ __launch_bounds__(512, 4) void sim_phaseC(
    const float* __restrict__ forces, const float* __restrict__ hm,
    const float* __restrict__ home,   const float* __restrict__ cs,
    const float* __restrict__ masses, const float* __restrict__ tens,
    const float* __restrict__ mics,   const float2* __restrict__ s0,
    float* __restrict__ out)
{
    __shared__ __align__(16) float sbuf[DD][64 * 20];   // 40 KB staging/dv
    __shared__ __align__(16) float lR[DD * 1028];       // 32.9 KB rv reduce
    int bm  = blockIdx.x >> 3;
    int grp = blockIdx.x & 7;
    int d    = threadIdx.x >> 6;
    int lane = threadIdx.x & 63;
    int sub = lane & 7;
    int cg  = lane >> 3;
    int m  = bm & (MM - 1);
    int ch = bm * DD + d;
    float ms  = masses[m];
    float k   = tens[m * DD + d] / ms;
    float csm = cs[m];
    float hd  = home[d];
    float mm  = ms * mics[m * DD + d];

    size_t gbase = (size_t)ch * NS + grp * 1024;
    float* sb = sbuf[d];
    int wp = (lane >> 2) * 20 + (lane & 3) * 4;

    // coalesced loads (all 8 up front)
    float4 f0 = *(const float4*)(forces + gbase + 0 * 256 + 4 * lane);
    float4 f1 = *(const float4*)(forces + gbase + 1 * 256 + 4 * lane);
    float4 f2 = *(const float4*)(forces + gbase + 2 * 256 + 4 * lane);
    float4 f3 = *(const float4*)(forces + gbase + 3 * 256 + 4 * lane);
    float4 h0 = *(const float4*)(hm + gbase + 0 * 256 + 4 * lane);
    float4 h1 = *(const float4*)(hm + gbase + 1 * 256 + 4 * lane);
    float4 h2 = *(const float4*)(hm + gbase + 2 * 256 + 4 * lane);
    float4 h3 = *(const float4*)(hm + gbase + 3 * 256 + 4 * lane);

    *(float4*)(sb + wp + 0 * 16 * 20) = f0;
    *(float4*)(sb + wp + 1 * 16 * 20) = f1;
    *(float4*)(sb + wp + 2 * 16 * 20) = f2;
    *(float4*)(sb + wp + 3 * 16 * 20) = f3;
    __syncthreads();
    float4 fq[4];
#pragma unroll
    for (int q = 0; q < 4; ++q)
        fq[q] = *(const float4*)(sb + lane * 20 + 4 * q);
    __syncthreads();
    *(float4*)(sb + wp + 0 * 16 * 20) = h0;
    *(float4*)(sb + wp + 1 * 16 * 20) = h1;
    *(float4*)(sb + wp + 2 * 16 * 20) = h2;
    *(float4*)(sb + wp + 3 * 16 * 20) = h3;
    __syncthreads();
    float4 hq[4];
#pragma unroll
    for (int q = 0; q < 4; ++q)
        hq[q] = *(const float4*)(sb + lane * 20 + 4 * q);
    const float* fr = (const float*)fq;
    const float* hr = (const float*)hq;

    // pass 1: forced response of this lane's window (zero state)
    float pos = 0.f, vel = 0.f;
#pragma unroll
    for (int i = 0; i < 16; ++i) {
        float ht  = fmaf(hr[i], csm, hd);
        float dir = ht - pos;
        float acc = fmaf(k, dir, fr[i]);
        vel = (vel + acc) * DAMP;
        pos += vel;
    }
    float Wx = pos, Wy = vel;

    // matrix powers for scan
    Mat A   = {1.f - DAMP * k, DAMP, -DAMP * k, DAMP};
    Mat A2  = matmul(A, A);
    Mat A4  = matmul(A2, A2);
    Mat A8  = matmul(A4, A4);
    Mat M0  = matmul(A8, A8);      // A^16
    Mat M1  = matmul(M0, M0);      // A^32
    Mat M2  = matmul(M1, M1);      // A^64
    Mat P = {1.f, 0.f, 0.f, 1.f};  // (A^16)^sub
    if (sub & 1) P = matmul(P, M0);
    if (sub & 2) P = matmul(P, M1);
    if (sub & 4) P = matmul(P, M2);

    // inclusive Kogge-Stone scan within 8-lane groups
    {
        float ox, oy;
        ox = __shfl_up(Wx, 1, 64); oy = __shfl_up(Wy, 1, 64);
        if (sub >= 1) { float nx = Wx + fmaf(M0.a, ox, M0.b * oy);
                        float ny = Wy + fmaf(M0.c, ox, M0.d * oy);
                        Wx = nx; Wy = ny; }
        ox = __shfl_up(Wx, 2, 64); oy = __shfl_up(Wy, 2, 64);
        if (sub >= 2) { float nx = Wx + fmaf(M1.a, ox, M1.b * oy);
                        float ny = Wy + fmaf(M1.c, ox, M1.d * oy);
                        Wx = nx; Wy = ny; }
        ox = __shfl_up(Wx, 4, 64); oy = __shfl_up(Wy, 4, 64);
        if (sub >= 4) { float nx = Wx + fmaf(M2.a, ox, M2.b * oy);
                        float ny = Wy + fmaf(M2.c, ox, M2.d * oy);
                        Wx = nx; Wy = ny; }
    }
    float Ex = __shfl_up(Wx, 1, 64);
    float Ey = __shfl_up(Wy, 1, 64);
    if (sub == 0) { Ex = 0.f; Ey = 0.f; }

    int c = grp * 8 + cg;
    float2 s0v = s0[ch * CHUNKS + c];
    pos = fmaf(P.a, s0v.x, fmaf(P.b, s0v.y, Ex));
    vel = fmaf(P.c, s0v.x, fmaf(P.d, s0v.y, Ey));

    // exact re-walk; dv -> sbuf (own window region), rv -> lR (swizzled)
#pragma unroll
    for (int q = 0; q < 4; ++q) {
        float dv[4], rv[4];
#pragma unroll
        for (int i = 0; i < 4; ++i) {
            float ff = fr[q * 4 + i], hh = hr[q * 4 + i];
            float ht  = fmaf(hh, csm, hd);
            float dir = ht - pos;
            float acc = fmaf(k, dir, ff);
            vel = (vel + acc) * DAMP;
            pos += vel;
            dv[i] = dir;
            rv[i] = mm * acc;
        }
        *(float4*)(sb + lane * 20 + 4 * q) =
            make_float4(dv[0], dv[1], dv[2], dv[3]);
        *(float4*)(&lR[d * 1028 + P_SWZ(lane * 16 + 4 * q)]) =
            make_float4(rv[0], rv[1], rv[2], rv[3]);
    }
    __syncthreads();

    // flush disp coalesced
#pragma unroll
    for (int i = 0; i < 4; ++i) {
        float4 v = *(const float4*)(sb + wp + i * 16 * 20);
        *(float4*)(out + DISP_OFF + gbase + i * 256 + 4 * lane) = v;
    }
    // d-reduce rec (coalesced write)
    int t0 = threadIdx.x * 2;
    int ts = P_SWZ(t0);
    float sx = 0.f, sy = 0.f;
#pragma unroll
    for (int dd2 = 0; dd2 < DD; ++dd2) {
        float2 v = *(const float2*)(&lR[dd2 * 1028 + ts]);
        sx += v.x; sy += v.y;
    }
    *(float2*)(out + REC_OFF + (size_t)bm * NS + grp * 1024 + t0) =
        make_float2(sx, sy);
}

// ---------------- HF kernel: noise + combined 256-tap FIR + lf add ----------
__global__ __launch_bounds__(256) void hf_kernel(
    const float* __restrict__ rec,
    const float* __restrict__ filters, const float* __restrict__ tfm,
    const float* __restrict__ bias,    const float* __restrict__ hf_gain,
    float* __restrict__ hf)
{
    __shared__ float up[SW(FL + SEG) + 8];
    __shared__ float gtap[FL];
    int bm  = blockIdx.x >> 2;
    int seg = blockIdx.x & 3;
    int b = bm >> 6;
    int m = bm & 63;
    int tx = threadIdx.x;
    int T0 = seg * SEG;

    float gs = 0.f;
#pragma unroll
    for (int f = 0; f < NF; ++f) {
        float mix = 0.f;
#pragma unroll
        for (int dd = 0; dd < DD; ++dd)
            mix = fmaf(bias[m * DD + dd], tfm[(m * DD + dd) * NF + f], mix);
        gs = fmaf(mix, filters[(b * NF + f) * FL + tx], gs);
    }
    gtap[tx] = gs;

    const float* rrow = rec + (size_t)bm * NS;
    for (int j = tx; j < FL + SEG; j += 256) {
        int t = T0 - FL + j;
        float v = 0.f;
        if (t >= 0) v = fabsf(rrow[t]) * jax_noise((unsigned)(bm * NS + t));
        up[SW(j)] = v;
    }
    __syncthreads();

    float gain = hf_gain[0];
    float* hrow = hf + (size_t)bm * NS;
    int t0 = tx * 8;
    float acc[8] = {0, 0, 0, 0, 0, 0, 0, 0};
    float w[8];
#pragma unroll
    for (int j = 0; j < 8; ++j) w[j] = up[SW(t0 + 1 + j)];
#pragma unroll 8
    for (int s = 255; s >= 1; --s) {
        float gv = gtap[s];
#pragma unroll
        for (int j = 0; j < 8; ++j) acc[j] = fmaf(gv, w[j], acc[j]);
#pragma unroll
        for (int j = 0; j < 7; ++j) w[j] = w[j + 1];
        w[7] = up[SW(FL + t0 + 8 - s)];
    }
    float g0 = gtap[0];
#pragma unroll
    for (int j = 0; j < 8; ++j) acc[j] = fmaf(g0, w[j], acc[j]);
    float4 r0 = *(const float4*)(rrow + T0 + t0);
    float4 r1 = *(const float4*)(rrow + T0 + t0 + 4);
    float4 o0 = make_float4(fmaf(gain, acc[0], r0.x), fmaf(gain, acc[1], r0.y),
                            fmaf(gain, acc[2], r0.z), fmaf(gain, acc[3], r0.w));
    float4 o1 = make_float4(fmaf(gain, acc[4], r1.x), fmaf(gain, acc[5], r1.y),
                            fmaf(gain, acc[6], r1.z), fmaf(gain, acc[7], r1.w));
    *(float4*)(hrow + T0 + t0)     = o0;
    *(float4*)(hrow + T0 + t0 + 4) = o1;
}

extern "C" void kernel_launch(void* const* d_in, const int* in_sizes, int n_in,
                              void* d_out, int out_size, void* d_ws, size_t ws_size,
                              hipStream_t stream)
{
    const float* forces  = (const float*)d_in[0];
    const float* hm      = (const float*)d_in[1];
    const float* filters = (const float*)d_in[2];
    const float* home    = (const float*)d_in[3];
    const float* cs      = (const float*)d_in[4];
    const float* masses  = (const float*)d_in[5];
    const float* tens    = (const float*)d_in[6];
    const float* mics    = (const float*)d_in[7];
    const float* tfm     = (const float*)d_in[8];
    const float* bias    = (const float*)d_in[9];
    const float* gain    = (const float*)d_in[10];
    float* out = (float*)d_out;

    float2* q  = (float2*)d_ws;                 // 1 MiB
    float2* s0 = q + NCHAIN * CHUNKS;           // 1 MiB

    sim_phaseA<<<4096, 256, 0, stream>>>(forces, hm, home, cs, masses, tens, q);
    sim_phaseB<<<NCHAIN / 256, 256, 0, stream>>>(masses, tens, q, s0);
    sim_phaseC<<<BB * MM * 8, 512, 0, stream>>>(
        forces, hm, home, cs, masses, tens, mics, s0, out);
    hf_kernel<<<BB * MM * 4, 256, 0, stream>>>(
        out + REC_OFF, filters, tfm, bias, gain, out + HF_OFF);
}